// Round 10
// baseline (35.540 us; speedup 1.0000x reference)
//
#include <hip/hip_runtime.h>

#define N_Q   50000
#define N_S   50000
#define M_NB  32
#define K_PTS 15
#define CIN   64
#define COUT  64
#define NGROUPS (N_Q / 2)          // 25000 groups of 2 query points
#define NBLOCKS 2048
#define WPB     4                  // waves per block
#define NWAVES  (NBLOCKS * WPB)    // 8192 resident waves = 32/CU

// Persistent waves, one group (2 query points) per iteration, ~3 iterations.
// Pipeline: neighbor idx prefetched 2 iters ahead; support xyz 1 iter ahead.
// Far/shadow sentinel (1e6,1e6,1e6) == reference's shadow point exactly.
//
// Sparsity (exact): w[k][m] = max(1 - d/0.05, 0), ||kp|| <= 0.0495 =>
// w > 0 requires ||nb||^2 < 0.009901 (0.0101 conservative). ~0.4% of pairs.
__global__ __launch_bounds__(256) void kpconv_fused3(
    const float* __restrict__ query,     // [N,3]
    const float* __restrict__ support,   // [N0,3]
    const int*   __restrict__ neighbors, // [N,M]
    const float* __restrict__ x,         // [N0,CIN]
    const float* __restrict__ kpts,      // [K,3]
    const float* __restrict__ weight,    // [K,CIN,COUT]
    float*       __restrict__ out)       // [N,COUT]
{
    __shared__ float s_kx[K_PTS], s_ky[K_PTS], s_kz[K_PTS], s_kk[K_PTS];
    __shared__ float s_bc[WPB][CIN];     // per-wave broadcast buffer

    const int tid = threadIdx.x;
    if (tid < K_PTS) {
        float kx = kpts[tid * 3 + 0];
        float ky = kpts[tid * 3 + 1];
        float kz = kpts[tid * 3 + 2];
        s_kx[tid] = kx; s_ky[tid] = ky; s_kz[tid] = kz;
        s_kk[tid] = kx * kx + ky * ky + kz * kz;   // same 3-term fp32 sum as ref
    }
    __syncthreads();

    const int wv   = tid >> 6;
    const int lane = tid & 63;
    const int h    = lane >> 5;                    // half: 0 -> point A, 1 -> B
    const int wid  = blockIdx.x * WPB + wv;        // 0..NWAVES-1

    // ---- pipeline prologue ----
    int gA   = wid;
    int idxA = (gA < NGROUPS) ? neighbors[gA * 64 + lane] : N_S;
    int gB   = gA + NWAVES;
    int idxB = (gB < NGROUPS) ? neighbors[gB * 64 + lane] : N_S;

    float sxA = 1e6f, syA = 1e6f, szA = 1e6f;      // shadow sentinel == ref
    if (idxA < N_S) {
        sxA = support[idxA * 3 + 0];
        syA = support[idxA * 3 + 1];
        szA = support[idxA * 3 + 2];
    }

    for (int g = wid; g < NGROUPS; g += NWAVES) {
        // prefetch neighbor idx two iterations ahead (independent VMEM)
        const int gNN  = g + 2 * NWAVES;
        const int idxC = (gNN < NGROUPS) ? neighbors[gNN * 64 + lane] : N_S;

        // prefetch support for NEXT group (idxB ready since last iteration)
        float sxB = 1e6f, syB = 1e6f, szB = 1e6f;
        if (idxB < N_S) {
            sxB = support[idxB * 3 + 0];
            syB = support[idxB * 3 + 1];
            szB = support[idxB * 3 + 2];
        }

        // ---- compute current group ----
        const int n = 2 * g + h;
        const float dx = sxA - query[n * 3 + 0];
        const float dy = syA - query[n * 3 + 1];
        const float dz = szA - query[n * 3 + 2];
        const float nn = dx * dx + dy * dy + dz * dz;   // shadow/far: huge

        float toutA = 0.f, toutB = 0.f;

        if (__ballot(nn < 0.0101f)) {              // ~23% of group-iterations
            const int idxCur = idxA;
            for (int k = 0; k < K_PTS; ++k) {
                float w = 0.f;
                if (nn < 0.0101f) {
                    float dot = dx * s_kx[k] + dy * s_ky[k] + dz * s_kz[k];
                    float sq  = fmaxf(nn - 2.f * dot + s_kk[k], 0.f); // ref expansion
                    if (sq < 0.0025f)              // sqrt(sq) < 0.05 => w > 0
                        w = 1.f - sqrtf(sq) * 20.f;  // 1/0.05 == 20 exactly
                }
                const unsigned long long em = __ballot(w > 0.f);
                if (!em) continue;                 // common: k has no hits

                const float* wk = weight + (size_t)k * CIN * COUT;

                unsigned emA = (unsigned)(em & 0xffffffffull);   // point A
                if (emA) {
                    float racc = 0.f;
                    do {
                        const int src = __builtin_ctz(emA); emA &= emA - 1;
                        const float wsrc = __shfl(w,      src);
                        const int   isrc = __shfl(idxCur, src);
                        racc = fmaf(wsrc, x[(size_t)isrc * CIN + lane], racc);
                    } while (emA);
                    s_bc[wv][lane] = racc;
                    asm volatile("" ::: "memory");
                    float p0 = 0.f, p1 = 0.f, p2 = 0.f, p3 = 0.f;
                    #pragma unroll 8
                    for (int c = 0; c < CIN; c += 4) {
                        p0 = fmaf(s_bc[wv][c + 0], wk[(c + 0) * COUT + lane], p0);
                        p1 = fmaf(s_bc[wv][c + 1], wk[(c + 1) * COUT + lane], p1);
                        p2 = fmaf(s_bc[wv][c + 2], wk[(c + 2) * COUT + lane], p2);
                        p3 = fmaf(s_bc[wv][c + 3], wk[(c + 3) * COUT + lane], p3);
                    }
                    toutA += (p0 + p1) + (p2 + p3);
                    asm volatile("" ::: "memory");
                }

                unsigned emB = (unsigned)(em >> 32);             // point B
                if (emB) {
                    float racc = 0.f;
                    do {
                        const int src = 32 + __builtin_ctz(emB); emB &= emB - 1;
                        const float wsrc = __shfl(w,      src);
                        const int   isrc = __shfl(idxCur, src);
                        racc = fmaf(wsrc, x[(size_t)isrc * CIN + lane], racc);
                    } while (emB);
                    s_bc[wv][lane] = racc;
                    asm volatile("" ::: "memory");
                    float p0 = 0.f, p1 = 0.f, p2 = 0.f, p3 = 0.f;
                    #pragma unroll 8
                    for (int c = 0; c < CIN; c += 4) {
                        p0 = fmaf(s_bc[wv][c + 0], wk[(c + 0) * COUT + lane], p0);
                        p1 = fmaf(s_bc[wv][c + 1], wk[(c + 1) * COUT + lane], p1);
                        p2 = fmaf(s_bc[wv][c + 2], wk[(c + 2) * COUT + lane], p2);
                        p3 = fmaf(s_bc[wv][c + 3], wk[(c + 3) * COUT + lane], p3);
                    }
                    toutB += (p0 + p1) + (p2 + p3);
                    asm volatile("" ::: "memory");
                }
            }
        }

        out[(size_t)(2 * g + 0) * COUT + lane] = toutA;   // wave owns both rows
        out[(size_t)(2 * g + 1) * COUT + lane] = toutB;

        // ---- rotate pipeline ----
        idxA = idxB; idxB = idxC;
        sxA = sxB; syA = syB; szA = szB;
    }
}

extern "C" void kernel_launch(void* const* d_in, const int* in_sizes, int n_in,
                              void* d_out, int out_size, void* d_ws, size_t ws_size,
                              hipStream_t stream) {
    const float* query     = (const float*)d_in[0];
    const float* support   = (const float*)d_in[1];
    const int*   neighbors = (const int*)  d_in[2];
    const float* x         = (const float*)d_in[3];
    const float* kpts      = (const float*)d_in[4];
    const float* weight    = (const float*)d_in[5];
    float*       out       = (float*)d_out;

    kpconv_fused3<<<NBLOCKS, 256, 0, stream>>>(
        query, support, neighbors, x, kpts, weight, out);
}

// Round 11
// 30.029 us; speedup vs baseline: 1.1835x; 1.1835x over previous
//
#include <hip/hip_runtime.h>

#define N_Q   50000
#define N_S   50000
#define M_NB  32
#define K_PTS 15
#define CIN   64
#define COUT  64
#define WPB   4                    // waves per block
#define PTS_PER_BLOCK (WPB * 2)    // 8 query points per block

// One wave per TWO query points: lanes 0-31 -> point A's 32 neighbors,
// lanes 32-63 -> point B's. Fully fused, no workspace, no atomics.
// 256-thread blocks (4 waves) -> 6250 workgroups total (dispatch-rate test).
//
// Sparsity (exact): w[k][m] = max(1 - d/0.05, 0), ||kp|| <= 0.0495, so w > 0
// requires ||nb||^2 < 0.009901 (0.0101 conservative). ~0.4% of pairs qualify.
__global__ __launch_bounds__(256) void kpconv_fused2(
    const float* __restrict__ query,     // [N,3]
    const float* __restrict__ support,   // [N0,3]
    const int*   __restrict__ neighbors, // [N,M]
    const float* __restrict__ x,         // [N0,CIN]
    const float* __restrict__ kpts,      // [K,3]
    const float* __restrict__ weight,    // [K,CIN,COUT]
    float*       __restrict__ out)       // [N,COUT]
{
    __shared__ float s_kx[K_PTS], s_ky[K_PTS], s_kz[K_PTS], s_kk[K_PTS];
    __shared__ float s_bc[WPB][CIN];     // per-wave broadcast buffer

    const int tid = threadIdx.x;
    if (tid < K_PTS) {
        float kx = kpts[tid * 3 + 0];
        float ky = kpts[tid * 3 + 1];
        float kz = kpts[tid * 3 + 2];
        s_kx[tid] = kx; s_ky[tid] = ky; s_kz[tid] = kz;
        s_kk[tid] = kx * kx + ky * ky + kz * kz;   // same 3-term fp32 sum as ref
    }
    __syncthreads();

    const int wv   = tid >> 6;                    // 0..3
    const int lane = tid & 63;
    const int base = blockIdx.x * PTS_PER_BLOCK + wv * 2;  // grid exact
    const int h    = lane >> 5;                   // half: 0 -> point A, 1 -> B
    const int n    = base + h;                    // this lane's query point
    const int m    = lane & 31;

    const int idx = neighbors[n * M_NB + m];      // coalesced (2 rows/wave)

    float dx = 0.f, dy = 0.f, dz = 0.f, nn = 1e30f;
    if (idx < N_S) {                              // idx==N_S: shadow, w==0
        dx = support[idx * 3 + 0] - query[n * 3 + 0];
        dy = support[idx * 3 + 1] - query[n * 3 + 1];
        dz = support[idx * 3 + 2] - query[n * 3 + 2];
        nn = dx * dx + dy * dy + dz * dz;
    }

    float toutA = 0.f, toutB = 0.f;

    if (__ballot(nn < 0.0101f)) {                 // ~23% of waves
        for (int k = 0; k < K_PTS; ++k) {
            float w = 0.f;
            if (nn < 0.0101f) {
                float dot = dx * s_kx[k] + dy * s_ky[k] + dz * s_kz[k];
                float sq  = fmaxf(nn - 2.f * dot + s_kk[k], 0.f);  // ref expansion
                if (sq < 0.0025f)                  // sqrt(sq) < 0.05 => w > 0
                    w = 1.f - sqrtf(sq) * 20.f;    // 1/0.05 == 20 exactly
            }
            const unsigned long long em = __ballot(w > 0.f);
            if (!em) continue;                     // common: k has no hits

            const float* wk = weight + (size_t)k * CIN * COUT;

            unsigned emA = (unsigned)(em & 0xffffffffull);   // point A events
            if (emA) {
                float racc = 0.f;
                do {
                    const int src = __builtin_ctz(emA); emA &= emA - 1;
                    const float wsrc = __shfl(w,   src);
                    const int   isrc = __shfl(idx, src);
                    racc = fmaf(wsrc, x[(size_t)isrc * CIN + lane], racc);
                } while (emA);
                s_bc[wv][lane] = racc;
                asm volatile("" ::: "memory");
                float p0 = 0.f, p1 = 0.f, p2 = 0.f, p3 = 0.f;
                #pragma unroll 8
                for (int c = 0; c < CIN; c += 4) {
                    p0 = fmaf(s_bc[wv][c + 0], wk[(c + 0) * COUT + lane], p0);
                    p1 = fmaf(s_bc[wv][c + 1], wk[(c + 1) * COUT + lane], p1);
                    p2 = fmaf(s_bc[wv][c + 2], wk[(c + 2) * COUT + lane], p2);
                    p3 = fmaf(s_bc[wv][c + 3], wk[(c + 3) * COUT + lane], p3);
                }
                toutA += (p0 + p1) + (p2 + p3);
                asm volatile("" ::: "memory");
            }

            unsigned emB = (unsigned)(em >> 32);             // point B events
            if (emB) {
                float racc = 0.f;
                do {
                    const int src = 32 + __builtin_ctz(emB); emB &= emB - 1;
                    const float wsrc = __shfl(w,   src);
                    const int   isrc = __shfl(idx, src);
                    racc = fmaf(wsrc, x[(size_t)isrc * CIN + lane], racc);
                } while (emB);
                s_bc[wv][lane] = racc;
                asm volatile("" ::: "memory");
                float p0 = 0.f, p1 = 0.f, p2 = 0.f, p3 = 0.f;
                #pragma unroll 8
                for (int c = 0; c < CIN; c += 4) {
                    p0 = fmaf(s_bc[wv][c + 0], wk[(c + 0) * COUT + lane], p0);
                    p1 = fmaf(s_bc[wv][c + 1], wk[(c + 1) * COUT + lane], p1);
                    p2 = fmaf(s_bc[wv][c + 2], wk[(c + 2) * COUT + lane], p2);
                    p3 = fmaf(s_bc[wv][c + 3], wk[(c + 3) * COUT + lane], p3);
                }
                toutB += (p0 + p1) + (p2 + p3);
                asm volatile("" ::: "memory");
            }
        }
    }

    out[(size_t)(base + 0) * COUT + lane] = toutA;  // wave owns both rows
    out[(size_t)(base + 1) * COUT + lane] = toutB;
}

extern "C" void kernel_launch(void* const* d_in, const int* in_sizes, int n_in,
                              void* d_out, int out_size, void* d_ws, size_t ws_size,
                              hipStream_t stream) {
    const float* query     = (const float*)d_in[0];
    const float* support   = (const float*)d_in[1];
    const int*   neighbors = (const int*)  d_in[2];
    const float* x         = (const float*)d_in[3];
    const float* kpts      = (const float*)d_in[4];
    const float* weight    = (const float*)d_in[5];
    float*       out       = (float*)d_out;

    kpconv_fused2<<<N_Q / PTS_PER_BLOCK, 256, 0, stream>>>(   // 6250 blocks
        query, support, neighbors, x, kpts, weight, out);
}